// Round 1
// baseline (437.543 us; speedup 1.0000x reference)
//
#include <hip/hip_runtime.h>
#include <hip/hip_bf16.h>
#include <cstdint>
#include <cstddef>

typedef short bf16x8 __attribute__((ext_vector_type(8)));
typedef float f32x4 __attribute__((ext_vector_type(4)));

__device__ __forceinline__ void gload_lds16(const void* g, void* l) {
  __builtin_amdgcn_global_load_lds((__attribute__((address_space(1))) const void*)g,
                                   (__attribute__((address_space(3))) void*)l, 16, 0, 0);
}

__device__ __forceinline__ unsigned short f2bf(float f) {
  unsigned u = __builtin_bit_cast(unsigned, f);
  u += 0x7fffu + ((u >> 16) & 1u);
  return (unsigned short)(u >> 16);
}
__device__ __forceinline__ float bf2f(unsigned short h) {
  unsigned u = ((unsigned)h) << 16;
  return __builtin_bit_cast(float, u);
}

// ---------------- cast f32 -> bf16 (vectorized) ----------------
__global__ void k_cast(const float* __restrict__ in, unsigned short* __restrict__ out, int n4) {
  int i = blockIdx.x * blockDim.x + threadIdx.x;
  int stride = gridDim.x * blockDim.x;
  for (; i < n4; i += stride) {
    float4 v = reinterpret_cast<const float4*>(in)[i];
    ushort4 o;
    o.x = f2bf(v.x); o.y = f2bf(v.y); o.z = f2bf(v.z); o.w = f2bf(v.w);
    reinterpret_cast<ushort4*>(out)[i] = o;
  }
}

// ---------------- GEMM: C[M,N] = A[M,K] * B[N,K]^T (bf16 in, f32 acc) ------
__device__ __forceinline__ void storeC(float* C, size_t i, float v) { C[i] = v; }
__device__ __forceinline__ void storeC(unsigned short* C, size_t i, float v) { C[i] = f2bf(v); }

template <typename OutT>
__global__ __launch_bounds__(256) void k_gemm_bt(
    const unsigned short* __restrict__ A,
    const unsigned short* __restrict__ B,
    OutT* __restrict__ C,
    int M, int N, int K) {
  __shared__ __align__(16) unsigned short lA[128 * 64];
  __shared__ __align__(16) unsigned short lB[128 * 64];
  const int tid = threadIdx.x;
  const int w = tid >> 6, l = tid & 63;
  const int m0 = blockIdx.x * 128, n0 = blockIdx.y * 128;
  const int wm = (w >> 1) * 64, wn = (w & 1) * 64;

  f32x4 acc[4][4];
#pragma unroll
  for (int i = 0; i < 4; ++i)
#pragma unroll
    for (int j = 0; j < 4; ++j) acc[i][j] = f32x4{0.f, 0.f, 0.f, 0.f};

  char* lAc = (char*)lA;
  char* lBc = (char*)lB;

  for (int k0 = 0; k0 < K; k0 += 64) {
#pragma unroll
    for (int p = 0; p < 4; ++p) {
      int r = (w * 4 + p) * 8 + (l >> 3);           // tile row 0..127
      int c = (l & 7) ^ (r & 7);                    // pre-swizzled source chunk
      gload_lds16(A + (size_t)(m0 + r) * K + k0 + c * 8, lAc + (w * 4 + p) * 1024);
      gload_lds16(B + (size_t)(n0 + r) * K + k0 + c * 8, lBc + (w * 4 + p) * 1024);
    }
    __syncthreads();
#pragma unroll
    for (int kk = 0; kk < 2; ++kk) {
      bf16x8 af[4], bfr[4];
#pragma unroll
      for (int i = 0; i < 4; ++i) {
        int r = wm + i * 16 + (l & 15);
        int slot = (kk * 4 + (l >> 4)) ^ (r & 7);
        af[i] = *(const bf16x8*)(lAc + r * 128 + slot * 16);
      }
#pragma unroll
      for (int j = 0; j < 4; ++j) {
        int r = wn + j * 16 + (l & 15);
        int slot = (kk * 4 + (l >> 4)) ^ (r & 7);
        bfr[j] = *(const bf16x8*)(lBc + r * 128 + slot * 16);
      }
#pragma unroll
      for (int i = 0; i < 4; ++i)
#pragma unroll
        for (int j = 0; j < 4; ++j)
          acc[i][j] = __builtin_amdgcn_mfma_f32_16x16x32_bf16(af[i], bfr[j], acc[i][j], 0, 0, 0);
    }
    __syncthreads();
  }

#pragma unroll
  for (int i = 0; i < 4; ++i)
#pragma unroll
    for (int j = 0; j < 4; ++j) {
      int row = m0 + wm + i * 16 + (l >> 4) * 4;
      int col = n0 + wn + j * 16 + (l & 15);
#pragma unroll
      for (int r = 0; r < 4; ++r)
        storeC(C, (size_t)(row + r) * N + col, acc[i][j][r]);
    }
}

// ---------------- RoPE on Q in place (+ fold 1/sqrt(HD)) ----------------
__global__ void k_rope_q(unsigned short* __restrict__ q,
                         const float* __restrict__ cosT, const float* __restrict__ sinT) {
  int idx = blockIdx.x * blockDim.x + threadIdx.x;
  if (idx >= 2048 * 32 * 64) return;
  int d0 = idx & 63;
  int h = (idx >> 6) & 31;
  int m = idx >> 11;
  int s = m & 1023;
  unsigned short* row = q + (size_t)m * 4096 + h * 128;
  float a = bf2f(row[d0]), b = bf2f(row[d0 + 64]);
  float c0 = cosT[s * 128 + d0], s0 = sinT[s * 128 + d0];
  float c1 = cosT[s * 128 + d0 + 64], s1 = sinT[s * 128 + d0 + 64];
  const float sc = 0.08838834764831845f;  // 128^-0.5
  row[d0] = f2bf((a * c0 - b * s0) * sc);
  row[d0 + 64] = f2bf((b * c1 + a * s1) * sc);
}

// ---------------- build K: concat(vision,text) + RoPE, head-major ----------
__global__ void k_build_k(const unsigned short* __restrict__ kvlin,  // [2048][1024], k = cols 0..511
                          const unsigned short* __restrict__ vkv,    // [512][1024],  k = cols 0..511
                          const float* __restrict__ cosT, const float* __restrict__ sinT,
                          unsigned short* __restrict__ k_all) {      // [8][1280][128]
  int idx = blockIdx.x * blockDim.x + threadIdx.x;
  if (idx >= 8 * 1280 * 64) return;
  int d0 = idx & 63;
  int t = (idx >> 6) % 1280;
  int bg = idx / (64 * 1280);
  int b = bg >> 2, g = bg & 3;
  float a, bb;
  if (t < 256) {
    const unsigned short* src = vkv + (size_t)(b * 256 + t) * 1024 + g * 128;
    a = bf2f(src[d0]); bb = bf2f(src[d0 + 64]);
  } else {
    const unsigned short* src = kvlin + (size_t)(b * 1024 + t - 256) * 1024 + g * 128;
    a = bf2f(src[d0]); bb = bf2f(src[d0 + 64]);
  }
  float c0 = cosT[t * 128 + d0], s0 = sinT[t * 128 + d0];
  float c1 = cosT[t * 128 + d0 + 64], s1 = sinT[t * 128 + d0 + 64];
  unsigned short* dst = k_all + ((size_t)bg * 1280 + t) * 128;
  dst[d0] = f2bf(a * c0 - bb * s0);
  dst[d0 + 64] = f2bf(bb * c1 + a * s1);
}

// ---------------- build V transposed: [8][128 d][1280 t] ----------------
__global__ void k_build_v(const unsigned short* __restrict__ kvlin,  // v = cols 512..1023
                          const unsigned short* __restrict__ vkv,    // v = cols 512..1023
                          unsigned short* __restrict__ v_t) {
  int idx = blockIdx.x * blockDim.x + threadIdx.x;
  if (idx >= 8 * 128 * 1280) return;
  int t = idx % 1280;
  int d = (idx / 1280) & 127;
  int bg = idx / (1280 * 128);
  int b = bg >> 2, g = bg & 3;
  unsigned short v;
  if (t < 256) v = vkv[(size_t)(b * 256 + t) * 1024 + 512 + g * 128 + d];
  else         v = kvlin[(size_t)(b * 1024 + t - 256) * 1024 + 512 + g * 128 + d];
  v_t[(size_t)bg * 128 * 1280 + (size_t)d * 1280 + t] = v;
}

// ---------------- flash attention ----------------
__global__ __launch_bounds__(256) void k_attn(
    const unsigned short* __restrict__ qr,     // [2048][4096] roped, pre-scaled
    const unsigned short* __restrict__ k_all,  // [8][1280][128]
    const unsigned short* __restrict__ v_t,    // [8][128][1280]
    unsigned short* __restrict__ attn) {       // [2048][4096]
  __shared__ __align__(16) unsigned short lK[64 * 128];
  __shared__ __align__(16) unsigned short lV[128 * 64];
  __shared__ __align__(16) unsigned short lP[4][16][72];

  const int tid = threadIdx.x, w = tid >> 6, l = tid & 63;
  const int qb = blockIdx.x * 64;
  const int h = blockIdx.y, b = blockIdx.z, g = h >> 3;
  const int bg = b * 4 + g;
  const unsigned short* kg = k_all + (size_t)bg * 1280 * 128;
  const unsigned short* vg = v_t + (size_t)bg * 128 * 1280;

  bf16x8 aq[4];
  {
    int row = qb + w * 16 + (l & 15);
    const unsigned short* p = qr + (size_t)(b * 1024 + row) * 4096 + h * 128 + (l >> 4) * 8;
    aq[0] = *(const bf16x8*)(p);
    aq[1] = *(const bf16x8*)(p + 32);
    aq[2] = *(const bf16x8*)(p + 64);
    aq[3] = *(const bf16x8*)(p + 96);
  }

  f32x4 o[8];
#pragma unroll
  for (int i = 0; i < 8; ++i) o[i] = f32x4{0.f, 0.f, 0.f, 0.f};
  float mr[4] = {-1e30f, -1e30f, -1e30f, -1e30f};
  float lr[4] = {0.f, 0.f, 0.f, 0.f};

  char* lKc = (char*)lK;
  char* lVc = (char*)lV;
  int tlim = qb + 320;
  if (tlim > 1280) tlim = 1280;

  for (int t0 = 0; t0 < tlim; t0 += 64) {
#pragma unroll
    for (int p = 0; p < 4; ++p) {  // K tile [64][128]
      int r = (w * 4 + p) * 4 + (l >> 4);
      int c = (l & 15) ^ (r & 7);
      gload_lds16(kg + (size_t)(t0 + r) * 128 + c * 8, lKc + (w * 4 + p) * 1024);
    }
#pragma unroll
    for (int p = 0; p < 4; ++p) {  // V tile [128][64]
      int d = (w * 4 + p) * 8 + (l >> 3);
      int c = (l & 7) ^ (d & 7);
      gload_lds16(vg + (size_t)d * 1280 + t0 + c * 8, lVc + (w * 4 + p) * 1024);
    }
    __syncthreads();

    f32x4 sfr[4];
#pragma unroll
    for (int sub = 0; sub < 4; ++sub) {
      f32x4 s4 = {0.f, 0.f, 0.f, 0.f};
      int krow = sub * 16 + (l & 15);
      const char* kb = lKc + krow * 256;
#pragma unroll
      for (int kk = 0; kk < 4; ++kk) {
        int slot = (kk * 4 + (l >> 4)) ^ (krow & 7);
        bf16x8 kf = *(const bf16x8*)(kb + slot * 16);
        s4 = __builtin_amdgcn_mfma_f32_16x16x32_bf16(aq[kk], kf, s4, 0, 0, 0);
      }
      int t = t0 + krow;
      int qrow_base = qb + w * 16 + (l >> 4) * 4;
#pragma unroll
      for (int r = 0; r < 4; ++r)
        if (t > qrow_base + r + 256) s4[r] = -1e30f;
      sfr[sub] = s4;
    }

    float scl[4], psum[4];
#pragma unroll
    for (int r = 0; r < 4; ++r) {
      float pm = fmaxf(fmaxf(sfr[0][r], sfr[1][r]), fmaxf(sfr[2][r], sfr[3][r]));
      pm = fmaxf(pm, __shfl_xor(pm, 1));
      pm = fmaxf(pm, __shfl_xor(pm, 2));
      pm = fmaxf(pm, __shfl_xor(pm, 4));
      pm = fmaxf(pm, __shfl_xor(pm, 8));
      float mnew = fmaxf(mr[r], pm);
      scl[r] = __expf(mr[r] - mnew);
      mr[r] = mnew;
      psum[r] = 0.f;
    }
#pragma unroll
    for (int sub = 0; sub < 4; ++sub)
#pragma unroll
      for (int r = 0; r < 4; ++r) {
        float p = __expf(sfr[sub][r] - mr[r]);
        psum[r] += p;
        lP[w][(l >> 4) * 4 + r][sub * 16 + (l & 15)] = f2bf(p);
      }
#pragma unroll
    for (int r = 0; r < 4; ++r) {
      float s = psum[r];
      s += __shfl_xor(s, 1);
      s += __shfl_xor(s, 2);
      s += __shfl_xor(s, 4);
      s += __shfl_xor(s, 8);
      lr[r] = lr[r] * scl[r] + s;
    }
#pragma unroll
    for (int cs = 0; cs < 8; ++cs) {
      o[cs][0] *= scl[0]; o[cs][1] *= scl[1];
      o[cs][2] *= scl[2]; o[cs][3] *= scl[3];
    }

    asm volatile("s_waitcnt lgkmcnt(0)" ::: "memory");

    bf16x8 pa0, pa1;
    {
      const char* pb = (const char*)&lP[w][l & 15][0];
      pa0 = *(const bf16x8*)(pb + (l >> 4) * 16);
      pa1 = *(const bf16x8*)(pb + 64 + (l >> 4) * 16);
    }
#pragma unroll
    for (int cs = 0; cs < 8; ++cs) {
      int drow = cs * 16 + (l & 15);
      const char* vb = lVc + drow * 128;
      int s0 = ((l >> 4)) ^ (drow & 7);
      int s1 = (4 + (l >> 4)) ^ (drow & 7);
      bf16x8 v0 = *(const bf16x8*)(vb + s0 * 16);
      bf16x8 v1 = *(const bf16x8*)(vb + s1 * 16);
      o[cs] = __builtin_amdgcn_mfma_f32_16x16x32_bf16(pa0, v0, o[cs], 0, 0, 0);
      o[cs] = __builtin_amdgcn_mfma_f32_16x16x32_bf16(pa1, v1, o[cs], 0, 0, 0);
    }
    __syncthreads();
  }

  float inv[4];
#pragma unroll
  for (int r = 0; r < 4; ++r) inv[r] = 1.0f / lr[r];
#pragma unroll
  for (int cs = 0; cs < 8; ++cs)
#pragma unroll
    for (int r = 0; r < 4; ++r) {
      int row = qb + w * 16 + (l >> 4) * 4 + r;
      attn[(size_t)(b * 1024 + row) * 4096 + h * 128 + cs * 16 + (l & 15)] =
          f2bf(o[cs][r] * inv[r]);
    }
}

// ---------------- launcher ----------------
extern "C" void kernel_launch(void* const* d_in, const int* in_sizes, int n_in,
                              void* d_out, int out_size, void* d_ws, size_t ws_size,
                              hipStream_t stream) {
  const float* x    = (const float*)d_in[0];
  const float* vis  = (const float*)d_in[1];
  const float* wq   = (const float*)d_in[2];
  const float* wk   = (const float*)d_in[3];
  const float* wv   = (const float*)d_in[4];
  const float* wo   = (const float*)d_in[5];
  const float* wvkv = (const float*)d_in[6];
  const float* cosT = (const float*)d_in[7];
  const float* sinT = (const float*)d_in[8];
  float* out = (float*)d_out;
  char* ws = (char*)d_ws;

  size_t off = 0;
  auto alloc = [&](size_t b) { size_t r = off; off += (b + 255) & ~(size_t)255; return r; };
  unsigned short* wqb   = (unsigned short*)(ws + alloc((size_t)4096 * 4096 * 2));
  unsigned short* wob   = (unsigned short*)(ws + alloc((size_t)4096 * 4096 * 2));
  unsigned short* wkvb  = (unsigned short*)(ws + alloc((size_t)1024 * 4096 * 2));
  unsigned short* wvkvb = (unsigned short*)(ws + alloc((size_t)1024 * 768 * 2));
  unsigned short* visb  = (unsigned short*)(ws + alloc((size_t)512 * 768 * 2));
  unsigned short* xb    = (unsigned short*)(ws + alloc((size_t)2048 * 4096 * 2));
  unsigned short* qbuf  = (unsigned short*)(ws + alloc((size_t)2048 * 4096 * 2));
  unsigned short* kvlin = (unsigned short*)(ws + alloc((size_t)2048 * 1024 * 2));
  unsigned short* vkvb  = (unsigned short*)(ws + alloc((size_t)512 * 1024 * 2));
  unsigned short* kall  = (unsigned short*)(ws + alloc((size_t)8 * 1280 * 128 * 2));
  unsigned short* vt    = (unsigned short*)(ws + alloc((size_t)8 * 128 * 1280 * 2));
  unsigned short* attnb = xb;  // x is dead after the projections; reuse
  if (ws_size < off) return;

  auto cast = [&](const float* src, unsigned short* dst, size_t n) {
    int n4 = (int)(n / 4);
    int grid = (n4 + 255) / 256;
    if (grid > 1280) grid = 1280;
    k_cast<<<dim3(grid), dim3(256), 0, stream>>>(src, dst, n4);
  };
  cast(x, xb, (size_t)2048 * 4096);
  cast(wq, wqb, (size_t)4096 * 4096);
  cast(wk, wkvb, (size_t)512 * 4096);
  cast(wv, wkvb + (size_t)512 * 4096, (size_t)512 * 4096);
  cast(wo, wob, (size_t)4096 * 4096);
  cast(wvkv, wvkvb, (size_t)1024 * 768);
  cast(vis, visb, (size_t)512 * 768);

  k_gemm_bt<unsigned short><<<dim3(16, 32), dim3(256), 0, stream>>>(xb, wqb, qbuf, 2048, 4096, 4096);
  k_gemm_bt<unsigned short><<<dim3(16, 8), dim3(256), 0, stream>>>(xb, wkvb, kvlin, 2048, 1024, 4096);
  k_gemm_bt<unsigned short><<<dim3(4, 8), dim3(256), 0, stream>>>(visb, wvkvb, vkvb, 512, 1024, 768);

  k_rope_q<<<dim3(16384), dim3(256), 0, stream>>>(qbuf, cosT, sinT);
  k_build_k<<<dim3(2560), dim3(256), 0, stream>>>(kvlin, vkvb, cosT, sinT, kall);
  k_build_v<<<dim3(5120), dim3(256), 0, stream>>>(kvlin, vkvb, vt);

  k_attn<<<dim3(16, 32, 2), dim3(256), 0, stream>>>(qbuf, kall, vt, attnb);

  k_gemm_bt<float><<<dim3(16, 32), dim3(256), 0, stream>>>(attnb, wob, out, 2048, 4096, 4096);
}